// Round 9
// baseline (383.371 us; speedup 1.0000x reference)
//
#include <hip/hip_runtime.h>
#include <hip/hip_fp16.h>
#include <stdint.h>

#define FD 128
#define CAP 4096
#define PSH 8                 // 256 nodes per partition
#define NPART_MAX 512
#define NBLK1 1024            // build blocks; chunk = ceil(E/NBLK1) <= EBUF_MAX
#define EBUF_MAX 4096
#define SCORE_BLKS 2048
#define TRANS_BLKS 448        // 896 virtual rows, 2 per block

static inline size_t alignup256(size_t x) { return (x + 255) & ~(size_t)255; }

struct EdgeP { int s; float w; };

typedef __attribute__((ext_vector_type(4))) float f32x4;
typedef __attribute__((ext_vector_type(8))) short bf16x8;

__device__ __forceinline__ unsigned short f32_to_bf16(float f) {
  unsigned u = __float_as_uint(f);
  u += 0x7fffu + ((u >> 16) & 1u);
  return (unsigned short)(u >> 16);
}
__device__ __forceinline__ unsigned pack_bf16(float a, float b) {
  return ((unsigned)f32_to_bf16(b) << 16) | (unsigned)f32_to_bf16(a);
}
// f16 payload for xb: consume side fuses cvt+fma into v_fma_mix_f32.
__device__ __forceinline__ unsigned pack_f16(float a, float b) {
  unsigned short ha = __half_as_ushort(__float2half_rn(a));
  unsigned short hb = __half_as_ushort(__float2half_rn(b));
  return ((unsigned)hb << 16) | (unsigned)ha;
}
__device__ __forceinline__ float f16lo(unsigned u) {
  return __half2float(__ushort_as_half((unsigned short)(u & 0xffffu)));
}
__device__ __forceinline__ float f16hi(unsigned u) {
  return __half2float(__ushort_as_half((unsigned short)(u >> 16)));
}
__device__ __forceinline__ unsigned mono32(float f) {
  unsigned u = __float_as_uint(f);
  return (u & 0x80000000u) ? ~u : (u | 0x80000000u);
}
__device__ __forceinline__ unsigned long long mono64(double d) {
  unsigned long long b = (unsigned long long)__double_as_longlong(d);
  return (b & 0x8000000000000000ULL) ? ~b : (b | 0x8000000000000000ULL);
}

// ============ L1: score_pack || part_count || transpose3 (256 thr) ============
__global__ __launch_bounds__(256)
void k_front(const float* __restrict__ x, const float* __restrict__ pvec,
             double* __restrict__ dvals, unsigned* __restrict__ hist,
             unsigned short* __restrict__ xb, unsigned* __restrict__ cnt, int N,
             const int* __restrict__ dstA, unsigned* __restrict__ pcnt, int E, int NPART,
             const float* __restrict__ w_ih, const float* __restrict__ w_hh,
             const float* __restrict__ w_lin, float* __restrict__ w_ihT,
             float* __restrict__ w_hhT, unsigned short* __restrict__ wlb)
{
  int b = blockIdx.x, t = threadIdx.x;
  if (b < SCORE_BLKS) {
    // ---- score_pack: f64 dot(x_row, p) + f16 pack of x ----
    int gid = b * 256 + t;
    if (gid == 0) *cnt = 0u;
    int wid = gid >> 6, lane = t & 63;
    const int nw = (SCORE_BLKS * 256) >> 6;
    double p0 = (double)pvec[lane * 2], p1 = (double)pvec[lane * 2 + 1];
    for (int n = wid; n < N; n += nw) {
      float2 xv = *(const float2*)(x + (size_t)n * FD + lane * 2);
      unsigned pk = pack_f16(xv.x, xv.y);
      *(unsigned*)(xb + (size_t)n * FD + lane * 2) = pk;
      double s = (double)xv.x * p0 + (double)xv.y * p1;
      #pragma unroll
      for (int o = 32; o > 0; o >>= 1) s += __shfl_down(s, o, 64);
      if (lane == 0) {
        dvals[n] = s;
        unsigned u = mono32((float)s);
        atomicAdd(&hist[u >> 16], 1u);
      }
    }
  } else if (b < SCORE_BLKS + NBLK1) {
    // ---- part_count: per-(partition, block) counts ----
    __shared__ unsigned lh[NPART_MAX];
    int bid = b - SCORE_BLKS;
    for (int i = t; i < NPART; i += 256) lh[i] = 0;
    __syncthreads();
    int chunk = (E + NBLK1 - 1) / NBLK1;
    int e0 = bid * chunk;
    int e1 = e0 + chunk; if (e1 > E) e1 = E;
    for (int e = e0 + t; e < e1; e += 256)
      atomicAdd(&lh[dstA[e] >> PSH], 1u);
    __syncthreads();
    for (int i = t; i < NPART; i += 256)
      pcnt[(size_t)i * NBLK1 + bid] = lh[i];
  } else {
    // ---- transpose3: 2 virtual rows per block ----
    int vb = (b - SCORE_BLKS - NBLK1) * 2 + (t >> 7);
    int c = t & 127;
    if (vb < 384)      w_ihT[(size_t)c * 384 + vb]         = w_ih[(size_t)vb * 128 + c];
    else if (vb < 768) w_hhT[(size_t)c * 384 + (vb - 384)] = w_hh[(size_t)(vb - 384) * 128 + c];
    else               wlb[(size_t)(vb - 768) * 128 + c]   = f32_to_bf16(w_lin[(size_t)(vb - 768) * 128 + c]);
  }
}

// ============ L2: find_thresh || scan_blocks (1024 thr) ============
// scan_blocks: wave-shfl inclusive scan (2 barriers instead of 20).
__global__ __launch_bounds__(1024)
void k_mid1(const unsigned* __restrict__ hist, unsigned* __restrict__ Bthr,
            const unsigned* __restrict__ pcnt, unsigned* __restrict__ basel,
            unsigned* __restrict__ ptot)
{
  int t = threadIdx.x;
  if (blockIdx.x == 0) {
    // ---- find_thresh ----
    __shared__ unsigned part[1024];
    unsigned s = 0;
    for (int i = 0; i < 64; i++) s += hist[t * 64 + i];
    part[t] = s;
    __syncthreads();
    if (t == 0) {
      unsigned cum = 0;
      int chunk = 1023;
      for (; chunk >= 0; chunk--) {
        if (cum + part[chunk] >= 128u) break;
        cum += part[chunk];
      }
      unsigned B = 0;
      if (chunk >= 0) {
        int b = chunk * 64 + 63;
        for (; b >= chunk * 64; b--) {
          cum += hist[b];
          if (cum >= 128u) break;
        }
        B = (unsigned)b;
      }
      *Bthr = B;
    }
  } else {
    // ---- scan_blocks: wave-shfl scan over 1024 entries ----
    __shared__ unsigned wtot[16];
    int p = blockIdx.x - 1;
    int lane = t & 63, wv = t >> 6;
    unsigned c = pcnt[(size_t)p * NBLK1 + t];
    unsigned v = c;
    #pragma unroll
    for (int d = 1; d < 64; d <<= 1) {
      unsigned u = __shfl_up(v, d, 64);
      if (lane >= d) v += u;
    }
    if (lane == 63) wtot[wv] = v;
    __syncthreads();
    unsigned add = 0;
    #pragma unroll
    for (int w = 0; w < 16; w++) if (w < wv) add += wtot[w];
    v += add;
    basel[(size_t)p * NBLK1 + t] = v - c;
    if (t == NBLK1 - 1) ptot[p] = v;
  }
}

// ============ L3: part_place || compact (512 thr) ============
// part_place: wave-shfl double scan (lcnt + ptot) -> poff in-block; pbuf
// records partition at bucket time -> direct-lookup write-out.
__global__ __launch_bounds__(512)
void k_mid2(const int* __restrict__ srcA, const int* __restrict__ dstA,
            const float* __restrict__ ew, const unsigned* __restrict__ ptot,
            const unsigned* __restrict__ basel, unsigned long long* __restrict__ epk2,
            int E, int NPART,
            const double* __restrict__ dvals, const unsigned* __restrict__ Bthr,
            unsigned long long* __restrict__ ckey, unsigned* __restrict__ cidx,
            unsigned* __restrict__ cnt, int N)
{
  int t = threadIdx.x;
  if (blockIdx.x < NBLK1) {
    // ---- part_place ----
    __shared__ unsigned long long ebuf[EBUF_MAX];
    __shared__ unsigned short pbuf[EBUF_MAX];
    __shared__ unsigned lcnt[NPART_MAX];
    __shared__ unsigned lbase[NPART_MAX];
    __shared__ unsigned cur[NPART_MAX];
    __shared__ int gbase[NPART_MAX];
    __shared__ unsigned wt1[8], wt2[8];
    int b = blockIdx.x;
    int chunk = (E + NBLK1 - 1) / NBLK1;
    int e0 = b * chunk;
    int e1 = e0 + chunk; if (e1 > E) e1 = E;
    int n = e1 - e0;

    lcnt[t] = 0;
    unsigned pt = (t < NPART) ? ptot[t] : 0u;
    __syncthreads();
    for (int e = e0 + t; e < e1; e += 512)
      atomicAdd(&lcnt[dstA[e] >> PSH], 1u);
    __syncthreads();
    int lane = t & 63, wv = t >> 6;
    unsigned c1 = lcnt[t];
    unsigned v1 = c1, v2 = pt;
    #pragma unroll
    for (int d = 1; d < 64; d <<= 1) {
      unsigned u1 = __shfl_up(v1, d, 64);
      unsigned u2 = __shfl_up(v2, d, 64);
      if (lane >= d) { v1 += u1; v2 += u2; }
    }
    if (lane == 63) { wt1[wv] = v1; wt2[wv] = v2; }
    __syncthreads();
    unsigned a1 = 0, a2 = 0;
    #pragma unroll
    for (int w = 0; w < 8; w++) if (w < wv) { a1 += wt1[w]; a2 += wt2[w]; }
    v1 += a1; v2 += a2;
    lbase[t] = v1 - c1;
    cur[t] = v1 - c1;
    gbase[t] = (t < NPART) ? ((int)(v2 - pt) + (int)basel[(size_t)t * NBLK1 + b]) : 0;
    __syncthreads();
    for (int e = e0 + t; e < e1; e += 512) {
      int d = dstA[e];
      int s = srcA[e];
      float w = ew[e];
      int p = d >> PSH;
      unsigned long long v = ((unsigned long long)__float_as_uint(w) << 32)
                           | ((unsigned long long)(unsigned)s << 8)
                           | (unsigned long long)(d & 255);
      unsigned pos = atomicAdd(&cur[p], 1u);
      ebuf[pos] = v;
      pbuf[pos] = (unsigned short)p;
    }
    __syncthreads();
    for (int j = t; j < n; j += 512) {
      int p = pbuf[j];
      epk2[gbase[p] + (j - (int)lbase[p])] = ebuf[j];
    }
  } else {
    // ---- compact: candidates with bin >= B ----
    int i = (blockIdx.x - NBLK1) * 512 + t;
    if (i >= N) return;
    unsigned B = *Bthr;
    double d = dvals[i];
    unsigned u = mono32((float)d);
    if ((u >> 16) >= B) {
      unsigned pos = atomicAdd(cnt, 1u);
      if (pos < CAP) {
        ckey[pos] = ~mono64(d);
        cidx[pos] = (unsigned)i;
      }
    }
  }
}

// ============ L4: topk_sort || part_csr (512 thr) ============
// part_csr: wave-shfl rsum reduce + wave-shfl 256-entry scan.
__global__ __launch_bounds__(512)
void k_mid3(const double* __restrict__ dvals, const float* __restrict__ pvec,
            const unsigned* __restrict__ cnt,
            const unsigned long long* __restrict__ ckey, const unsigned* __restrict__ cidx,
            unsigned* __restrict__ sel_idx, float* __restrict__ sel_ts,
            const unsigned* __restrict__ ptot, const unsigned long long* __restrict__ epk2,
            EdgeP* __restrict__ epk_out, int* __restrict__ off,
            float* __restrict__ dinv, int N, int NPART)
{
  int t = threadIdx.x;
  if (blockIdx.x == 0) {
    // ---- topk_sort (512-thread bitonic) ----
    __shared__ unsigned long long k[CAP];
    __shared__ unsigned id[CAP];
    __shared__ double red[128];
    __shared__ double pn_sh;
    unsigned C = *cnt;
    if (C > CAP) C = CAP;
    int S = 128;
    while (S < (int)C) S <<= 1;
    for (int i = t; i < S; i += 512) {
      if (i < (int)C) { k[i] = ckey[i]; id[i] = cidx[i]; }
      else            { k[i] = ~0ULL;   id[i] = 0xFFFFFFFFu; }
    }
    __syncthreads();
    for (int kk = 2; kk <= S; kk <<= 1) {
      for (int j = kk >> 1; j > 0; j >>= 1) {
        for (int i = t; i < S; i += 512) {
          int q = i ^ j;
          if (q > i) {
            bool up = ((i & kk) == 0);
            bool g = (k[i] > k[q]) || (k[i] == k[q] && id[i] > id[q]);
            if (g == up) {
              unsigned long long tk = k[i]; k[i] = k[q]; k[q] = tk;
              unsigned ti = id[i]; id[i] = id[q]; id[q] = ti;
            }
          }
        }
        __syncthreads();
      }
    }
    if (t < 128) { double v = (double)pvec[t]; red[t] = v * v; }
    __syncthreads();
    if (t == 0) {
      double s = 0.0;
      for (int i = 0; i < 128; i++) s += red[i];
      pn_sh = sqrt(s);
    }
    __syncthreads();
    if (t < 128) {
      unsigned n = id[t];
      sel_idx[t] = n;
      sel_ts[t] = (float)tanh(dvals[n] / pn_sh);
    }
  } else {
    // ---- part_csr ----
    int p = blockIdx.x - 1;
    int lane = t & 63, wv = t >> 6;
    __shared__ unsigned ws[8];
    __shared__ unsigned wt[4];
    __shared__ unsigned lcnt[256];
    __shared__ float ldeg[256];
    // beg = sum of ptot[0..p-1] via wave reduce (p < 512)
    unsigned a = (t < p) ? ptot[t] : 0u;
    #pragma unroll
    for (int d = 32; d > 0; d >>= 1) a += __shfl_xor(a, d, 64);
    if (lane == 0) ws[wv] = a;
    __syncthreads();
    unsigned bu = 0;
    #pragma unroll
    for (int w = 0; w < 8; w++) bu += ws[w];
    int beg = (int)bu;
    int end = beg + (int)ptot[p];

    int n0 = p << PSH;
    int nn = N - n0; if (nn > 256) nn = 256;
    if (t < 256) { lcnt[t] = 0; ldeg[t] = 0.f; }
    __syncthreads();
    for (int i = beg + t; i < end; i += 512) {
      unsigned long long v = epk2[i];
      int ln = (int)(v & 255u);
      float w = __uint_as_float((unsigned)(v >> 32));
      atomicAdd(&lcnt[ln], 1u);
      atomicAdd(&ldeg[ln], w);
    }
    __syncthreads();
    unsigned c = 0, v = 0;
    if (t < 256) {
      c = lcnt[t]; v = c;
      #pragma unroll
      for (int d = 1; d < 64; d <<= 1) {
        unsigned u = __shfl_up(v, d, 64);
        if (lane >= d) v += u;
      }
    }
    if (t < 256 && lane == 63) wt[wv] = v;
    __syncthreads();
    unsigned excl = 0;
    if (t < 256) {
      unsigned add = 0;
      #pragma unroll
      for (int w = 0; w < 4; w++) if (w < wv) add += wt[w];
      v += add;
      excl = v - c;
    }
    if (t < nn) {
      off[n0 + t] = beg + (int)excl;
      dinv[n0 + t] = rsqrtf(ldeg[t] + 1.0f);  // +1 = self loop
    }
    if (p == NPART - 1 && t == 0) off[N] = end;
    if (t < 256) lcnt[t] = excl;  // reuse as running cursor
    __syncthreads();
    for (int i = beg + t; i < end; i += 512) {
      unsigned long long vv = epk2[i];
      int ln = (int)(vv & 255u);
      unsigned q = atomicAdd(&lcnt[ln], 1u);
      EdgeP ep;
      ep.s = (int)((vv >> 8) & 0xFFFFFFu);
      ep.w = __uint_as_float((unsigned)(vv >> 32));
      epk_out[beg + (int)q] = ep;
    }
  }
}

// ============ L5 (x3 pieces): gru_evolve || csr_gather4 (256 thr) ============
// Gather split into 3 sequential node-range pieces (~38us each) so the top-5
// profiler table reveals the largest non-gather kernel. gru rides in piece 1.
__global__ __launch_bounds__(256)
void k_gg(const float* __restrict__ x, const unsigned* __restrict__ sel_idx,
          const float* __restrict__ sel_ts,
          const float* __restrict__ w_ihT, const float* __restrict__ w_hhT,
          const float* __restrict__ b_ih, const float* __restrict__ b_hh,
          const float* __restrict__ w0, unsigned short* __restrict__ WbT,
          const int* __restrict__ off, const EdgeP* __restrict__ epk,
          const float* __restrict__ dinv, const unsigned short* __restrict__ xb,
          unsigned short* __restrict__ aggb, int nbeg, int nend, int ngru)
{
  int t = threadIdx.x;
  if (blockIdx.x < (unsigned)ngru) {
    // ---- gru_evolve (256 thr): thread t handles gate cols t and 256+t(<384) ----
    __shared__ float xt[FD], w0r[FD];
    __shared__ float gi[384], gh[384];
    int i = blockIdx.x;
    if (t < FD) {
      unsigned n = sel_idx[i];
      float ts = sel_ts[i];
      xt[t]  = x[(size_t)n * FD + t] * ts;
      w0r[t] = w0[i * FD + t];
    }
    __syncthreads();
    bool has2 = t < 128;
    float ga0 = b_ih[t], ha0 = b_hh[t];
    float ga1 = 0.f, ha1 = 0.f;
    if (has2) { ga1 = b_ih[256 + t]; ha1 = b_hh[256 + t]; }
    for (int kx = 0; kx < FD; kx++) {
      float xv = xt[kx], hv = w0r[kx];
      const float* wi = w_ihT + (size_t)kx * 384;
      const float* wh = w_hhT + (size_t)kx * 384;
      ga0 += xv * wi[t];
      ha0 += hv * wh[t];
      if (has2) {
        ga1 += xv * wi[256 + t];
        ha1 += hv * wh[256 + t];
      }
    }
    gi[t] = ga0; gh[t] = ha0;
    if (has2) { gi[256 + t] = ga1; gh[256 + t] = ha1; }
    __syncthreads();
    if (t < FD) {
      float r = 1.f / (1.f + expf(-(gi[t] + gh[t])));
      float z = 1.f / (1.f + expf(-(gi[128 + t] + gh[128 + t])));
      float nn = tanhf(gi[256 + t] + r * gh[256 + t]);
      float wv = (1.f - z) * nn + z * w0r[t];
      WbT[(size_t)t * FD + i] = f32_to_bf16(wv);
    }
  } else {
    // ---- csr_gather4: 4-deep (16 edges/step), group-uniform edge loads ----
    int gid = (blockIdx.x - ngru) * 256 + t;
    int wid = nbeg + (gid >> 6), lane = t & 63;
    if (wid >= nend) return;
    int g = lane >> 4, sub = lane & 15;
    int n = wid;
    int beg = off[n], end = off[n + 1];
    int cnt = end - beg;
    const EdgeP* ep_base = epk + beg;

    float di = dinv[n];
    uint4 xs4 = *(const uint4*)(xb + (size_t)n * FD + sub * 8);

    float acc[8];
    #pragma unroll
    for (int j = 0; j < 8; j++) acc[j] = 0.f;

    int nfull = cnt >> 4;
    int base = 0;
    for (int s16 = 0; s16 < nfull; s16++, base += 16) {
      uint2 ep[4];
      #pragma unroll
      for (int u = 0; u < 4; u++)
        ep[u] = *(const uint2*)(ep_base + base + u * 4 + g);
      float dv[4]; uint4 pv[4];
      #pragma unroll
      for (int u = 0; u < 4; u++) {
        int s = (int)ep[u].x;
        dv[u] = dinv[s];
        pv[u] = *(const uint4*)(xb + (size_t)s * FD + sub * 8);
      }
      #pragma unroll
      for (int u = 0; u < 4; u++) {
        float w = __uint_as_float(ep[u].y) * dv[u];
        acc[0] = fmaf(f16lo(pv[u].x), w, acc[0]); acc[1] = fmaf(f16hi(pv[u].x), w, acc[1]);
        acc[2] = fmaf(f16lo(pv[u].y), w, acc[2]); acc[3] = fmaf(f16hi(pv[u].y), w, acc[3]);
        acc[4] = fmaf(f16lo(pv[u].z), w, acc[4]); acc[5] = fmaf(f16hi(pv[u].z), w, acc[5]);
        acc[6] = fmaf(f16lo(pv[u].w), w, acc[6]); acc[7] = fmaf(f16hi(pv[u].w), w, acc[7]);
      }
    }
    if (base < cnt) {
      int last = cnt - 1;
      uint2 ep[4];
      #pragma unroll
      for (int u = 0; u < 4; u++) {
        int idx = base + u * 4 + g;
        int idc = idx < cnt ? idx : last;
        ep[u] = *(const uint2*)(ep_base + idc);
      }
      float dv[4]; uint4 pv[4];
      #pragma unroll
      for (int u = 0; u < 4; u++) {
        int s = (int)ep[u].x;
        dv[u] = dinv[s];
        pv[u] = *(const uint4*)(xb + (size_t)s * FD + sub * 8);
      }
      #pragma unroll
      for (int u = 0; u < 4; u++) {
        int idx = base + u * 4 + g;
        float w = (idx < cnt) ? __uint_as_float(ep[u].y) * dv[u] : 0.f;
        acc[0] = fmaf(f16lo(pv[u].x), w, acc[0]); acc[1] = fmaf(f16hi(pv[u].x), w, acc[1]);
        acc[2] = fmaf(f16lo(pv[u].y), w, acc[2]); acc[3] = fmaf(f16hi(pv[u].y), w, acc[3]);
        acc[4] = fmaf(f16lo(pv[u].z), w, acc[4]); acc[5] = fmaf(f16hi(pv[u].z), w, acc[5]);
        acc[6] = fmaf(f16lo(pv[u].w), w, acc[6]); acc[7] = fmaf(f16hi(pv[u].w), w, acc[7]);
      }
    }

    #pragma unroll
    for (int j = 0; j < 8; j++) {
      acc[j] += __shfl_xor(acc[j], 16, 64);
      acc[j] += __shfl_xor(acc[j], 32, 64);
    }
    if (g == 0) {
      float dii = di * di;
      uint4 o;
      o.x = pack_bf16(di * acc[0] + dii * f16lo(xs4.x), di * acc[1] + dii * f16hi(xs4.x));
      o.y = pack_bf16(di * acc[2] + dii * f16lo(xs4.y), di * acc[3] + dii * f16hi(xs4.y));
      o.z = pack_bf16(di * acc[4] + dii * f16lo(xs4.z), di * acc[5] + dii * f16hi(xs4.z));
      o.w = pack_bf16(di * acc[6] + dii * f16lo(xs4.w), di * acc[7] + dii * f16hi(xs4.w));
      *(uint4*)(aggb + (size_t)n * FD + sub * 8) = o;
    }
  }
}

// ---- MFMA epilogue: out = relu(aggb·W)·w_lin^T + b ----
__global__ __launch_bounds__(256)
void gemm_mfma(const unsigned short* __restrict__ aggb, const unsigned short* __restrict__ WbT,
               const unsigned short* __restrict__ wlb, const float* __restrict__ bias,
               float* __restrict__ C, int nrows)
{
  __shared__ unsigned short hs[64][136];  // +8 bf16 pad: 272B row stride
  int tid = threadIdx.x;
  int wv = tid >> 6, lane = tid & 63;
  int row16 = lane & 15;
  int kgrp = lane >> 4;
  int r0 = blockIdx.x * 64;
  int arow = r0 + wv * 16 + row16;
  bool rowok = arow < nrows;

  f32x4 acc[8];
  #pragma unroll
  for (int t = 0; t < 8; t++) acc[t] = (f32x4){0.f, 0.f, 0.f, 0.f};

  #pragma unroll
  for (int ks = 0; ks < 4; ks++) {
    int k = ks * 32 + kgrp * 8;
    bf16x8 a;
    if (rowok) a = *(const bf16x8*)(aggb + (size_t)arow * FD + k);
    else       a = (bf16x8){0, 0, 0, 0, 0, 0, 0, 0};
    #pragma unroll
    for (int t = 0; t < 8; t++) {
      int col = t * 16 + row16;
      bf16x8 b = *(const bf16x8*)(WbT + (size_t)col * FD + k);
      acc[t] = __builtin_amdgcn_mfma_f32_16x16x32_bf16(a, b, acc[t], 0, 0, 0);
    }
  }
  #pragma unroll
  for (int t = 0; t < 8; t++) {
    int col = t * 16 + row16;
    #pragma unroll
    for (int r = 0; r < 4; r++) {
      int row_l = wv * 16 + kgrp * 4 + r;
      hs[row_l][col] = f32_to_bf16(fmaxf(acc[t][r], 0.f));
    }
  }
  __syncthreads();

  f32x4 acc2[8];
  #pragma unroll
  for (int t = 0; t < 8; t++) acc2[t] = (f32x4){0.f, 0.f, 0.f, 0.f};
  #pragma unroll
  for (int ks = 0; ks < 4; ks++) {
    int k = ks * 32 + kgrp * 8;
    bf16x8 a = *(const bf16x8*)(&hs[wv * 16 + row16][k]);
    #pragma unroll
    for (int t = 0; t < 8; t++) {
      int col = t * 16 + row16;
      bf16x8 b = *(const bf16x8*)(wlb + (size_t)col * FD + k);
      acc2[t] = __builtin_amdgcn_mfma_f32_16x16x32_bf16(a, b, acc2[t], 0, 0, 0);
    }
  }
  #pragma unroll
  for (int t = 0; t < 8; t++) {
    int col = t * 16 + row16;
    float bl = bias[col];
    #pragma unroll
    for (int r = 0; r < 4; r++) {
      int row = r0 + wv * 16 + kgrp * 4 + r;
      if (row < nrows) C[(size_t)row * FD + col] = acc2[t][r] + bl;
    }
  }
}

extern "C" void kernel_launch(void* const* d_in, const int* in_sizes, int n_in,
                              void* d_out, int out_size, void* d_ws, size_t ws_size,
                              hipStream_t stream)
{
  const float* x     = (const float*)d_in[0];
  const float* ew    = (const float*)d_in[1];
  const float* pvec  = (const float*)d_in[2];
  const float* w_ih  = (const float*)d_in[3];
  const float* w_hh  = (const float*)d_in[4];
  const float* b_ih  = (const float*)d_in[5];
  const float* b_hh  = (const float*)d_in[6];
  const float* w0    = (const float*)d_in[7];
  const float* w_lin = (const float*)d_in[8];
  const float* b_lin = (const float*)d_in[9];
  const int*   eidx  = (const int*)d_in[10];

  int N = in_sizes[0] / FD;
  int E = in_sizes[1];
  int NPART = (N + 255) >> PSH;
  const int* srcA = eidx;
  const int* dstA = eidx + E;

  char* base = (char*)d_ws;
  size_t off_ws = 0;
  auto take = [&](size_t bytes) -> void* {
    void* ptr = base + off_ws;
    off_ws = alignup256(off_ws + bytes);
    return ptr;
  };
  double* dvals = (double*)take((size_t)N * 8);
  unsigned* hist = (unsigned*)take(65536u * 4);
  unsigned* cnt = (unsigned*)take(4);
  unsigned* Bthr = (unsigned*)take(4);
  unsigned long long* ckey = (unsigned long long*)take((size_t)CAP * 8);
  unsigned* cidx = (unsigned*)take((size_t)CAP * 4);
  unsigned* sel_idx = (unsigned*)take(128 * 4);
  float* sel_ts = (float*)take(128 * 4);
  unsigned short* WbT = (unsigned short*)take(FD * FD * 2);
  unsigned short* wlb = (unsigned short*)take(FD * FD * 2);
  float* w_ihT = (float*)take(3 * FD * FD * 4);
  float* w_hhT = (float*)take(3 * FD * FD * 4);
  float* dinv = (float*)take((size_t)N * 4);
  unsigned* pcnt = (unsigned*)take((size_t)NPART_MAX * NBLK1 * 4);
  unsigned* basel = (unsigned*)take((size_t)NPART_MAX * NBLK1 * 4);
  unsigned* ptot = (unsigned*)take((size_t)NPART_MAX * 4);
  int* off = (int*)take(((size_t)N + 1) * 4);
  unsigned long long* epk2 = (unsigned long long*)take((size_t)E * 8);
  EdgeP* epk_b = (EdgeP*)take((size_t)E * 8);
  unsigned short* xb = (unsigned short*)take((size_t)N * FD * 2);
  unsigned short* aggb = (unsigned short*)take((size_t)N * FD * 2);
  float* out1 = (float*)d_out;

  hipMemsetAsync(hist, 0, 65536u * 4, stream);

  // L1: score_pack || part_count || transpose3
  k_front<<<SCORE_BLKS + NBLK1 + TRANS_BLKS, 256, 0, stream>>>(
      x, pvec, dvals, hist, xb, cnt, N, dstA, pcnt, E, NPART,
      w_ih, w_hh, w_lin, w_ihT, w_hhT, wlb);
  // L2: find_thresh || scan_blocks
  k_mid1<<<1 + NPART, 1024, 0, stream>>>(hist, Bthr, pcnt, basel, ptot);
  // L3: part_place || compact
  k_mid2<<<NBLK1 + (N + 511) / 512, 512, 0, stream>>>(
      srcA, dstA, ew, ptot, basel, epk2, E, NPART,
      dvals, Bthr, ckey, cidx, cnt, N);
  // L4: topk_sort || part_csr
  k_mid3<<<1 + NPART, 512, 0, stream>>>(
      dvals, pvec, cnt, ckey, cidx, sel_idx, sel_ts,
      ptot, epk2, epk_b, off, dinv, N, NPART);
  // L5: gru_evolve || csr_gather4, split into 3 node-range pieces
  int n1 = (N + 2) / 3;
  int n2 = n1 * 2; if (n2 > N) n2 = N;
  k_gg<<<128 + (n1 + 3) / 4, 256, 0, stream>>>(
      x, sel_idx, sel_ts, w_ihT, w_hhT, b_ih, b_hh, w0, WbT,
      off, epk_b, dinv, xb, aggb, 0, n1, 128);
  k_gg<<<(n2 - n1 + 3) / 4, 256, 0, stream>>>(
      x, sel_idx, sel_ts, w_ihT, w_hhT, b_ih, b_hh, w0, WbT,
      off, epk_b, dinv, xb, aggb, n1, n2, 0);
  k_gg<<<(N - n2 + 3) / 4, 256, 0, stream>>>(
      x, sel_idx, sel_ts, w_ihT, w_hhT, b_ih, b_hh, w0, WbT,
      off, epk_b, dinv, xb, aggb, n2, N, 0);
  // L6: MFMA epilogue
  gemm_mfma<<<(N + 63) / 64, 256, 0, stream>>>(aggb, WbT, wlb, b_lin, out1, N);
}

// Round 10
// 351.900 us; speedup vs baseline: 1.0894x; 1.0894x over previous
//
#include <hip/hip_runtime.h>
#include <hip/hip_fp16.h>
#include <stdint.h>

#define FD 128
#define CAP 4096
#define PSH 8                 // 256 nodes per partition
#define NPART_MAX 512
#define NBLK1 1024            // build blocks; chunk = ceil(E/NBLK1) <= EBUF_MAX
#define EBUF_MAX 4096
#define SCORE_BLKS 2048
#define TRANS_BLKS 448        // 896 virtual rows, 2 per block

static inline size_t alignup256(size_t x) { return (x + 255) & ~(size_t)255; }

struct EdgeP { int s; float w; };

typedef __attribute__((ext_vector_type(4))) float f32x4;
typedef __attribute__((ext_vector_type(8))) short bf16x8;

__device__ __forceinline__ unsigned short f32_to_bf16(float f) {
  unsigned u = __float_as_uint(f);
  u += 0x7fffu + ((u >> 16) & 1u);
  return (unsigned short)(u >> 16);
}
__device__ __forceinline__ unsigned pack_bf16(float a, float b) {
  return ((unsigned)f32_to_bf16(b) << 16) | (unsigned)f32_to_bf16(a);
}
// f16 payload for xb: consume side fuses cvt+fma into v_fma_mix_f32.
__device__ __forceinline__ unsigned pack_f16(float a, float b) {
  unsigned short ha = __half_as_ushort(__float2half_rn(a));
  unsigned short hb = __half_as_ushort(__float2half_rn(b));
  return ((unsigned)hb << 16) | (unsigned)ha;
}
__device__ __forceinline__ float f16lo(unsigned u) {
  return __half2float(__ushort_as_half((unsigned short)(u & 0xffffu)));
}
__device__ __forceinline__ float f16hi(unsigned u) {
  return __half2float(__ushort_as_half((unsigned short)(u >> 16)));
}
__device__ __forceinline__ unsigned mono32(float f) {
  unsigned u = __float_as_uint(f);
  return (u & 0x80000000u) ? ~u : (u | 0x80000000u);
}
__device__ __forceinline__ unsigned long long mono64(double d) {
  unsigned long long b = (unsigned long long)__double_as_longlong(d);
  return (b & 0x8000000000000000ULL) ? ~b : (b | 0x8000000000000000ULL);
}

// ============ L1: score_pack || part_count || transpose3 (256 thr) ============
// Branch interleave: blocks 0..2047 alternate score/count so both phases
// co-reside on the machine (previously score's 2048 blocks filled capacity
// and serialized ahead of count). score is 4-deep unrolled: 4 independent
// dot-chains in flight per wave (per-node add order unchanged -> bitwise
// identical dvals). pcnt stored block-major (coalesced, no strided RMW).
__global__ __launch_bounds__(256)
void k_front(const float* __restrict__ x, const float* __restrict__ pvec,
             double* __restrict__ dvals, unsigned* __restrict__ hist,
             unsigned short* __restrict__ xb, unsigned* __restrict__ cnt, int N,
             const int* __restrict__ dstA, unsigned* __restrict__ pcnt, int E, int NPART,
             const float* __restrict__ w_ih, const float* __restrict__ w_hh,
             const float* __restrict__ w_lin, float* __restrict__ w_ihT,
             float* __restrict__ w_hhT, unsigned short* __restrict__ wlb)
{
  int b = blockIdx.x, t = threadIdx.x;
  int branch, bid;
  if (b < 2 * NBLK1)            { branch = (b & 1); bid = b >> 1; }
  else if (b < SCORE_BLKS + NBLK1) { branch = 0; bid = NBLK1 + (b - 2 * NBLK1); }
  else                          { branch = 2; bid = b - (SCORE_BLKS + NBLK1); }

  if (branch == 0) {
    // ---- score_pack: f64 dot(x_row, p) + f16 pack of x, 4-deep unroll ----
    int gid = bid * 256 + t;
    if (gid == 0) *cnt = 0u;
    int wid = gid >> 6, lane = t & 63;
    const int nw = (SCORE_BLKS * 256) >> 6;
    double p0 = (double)pvec[lane * 2], p1 = (double)pvec[lane * 2 + 1];
    for (int n0 = wid; n0 < N; n0 += 4 * nw) {
      int ns[4]; bool ok[4];
      float2 xv[4];
      #pragma unroll
      for (int u = 0; u < 4; u++) {
        ns[u] = n0 + u * nw;
        ok[u] = ns[u] < N;
        xv[u] = make_float2(0.f, 0.f);
        if (ok[u]) xv[u] = *(const float2*)(x + (size_t)ns[u] * FD + lane * 2);
      }
      #pragma unroll
      for (int u = 0; u < 4; u++)
        if (ok[u]) *(unsigned*)(xb + (size_t)ns[u] * FD + lane * 2) = pack_f16(xv[u].x, xv[u].y);
      double s[4];
      #pragma unroll
      for (int u = 0; u < 4; u++) s[u] = (double)xv[u].x * p0 + (double)xv[u].y * p1;
      #pragma unroll
      for (int o = 32; o > 0; o >>= 1) {
        #pragma unroll
        for (int u = 0; u < 4; u++) s[u] += __shfl_down(s[u], o, 64);
      }
      if (lane == 0) {
        #pragma unroll
        for (int u = 0; u < 4; u++) {
          if (ok[u]) {
            dvals[ns[u]] = s[u];
            atomicAdd(&hist[mono32((float)s[u]) >> 16], 1u);
          }
        }
      }
    }
  } else if (branch == 1) {
    // ---- part_count: per-(block, partition) counts, block-major store ----
    __shared__ unsigned lh[NPART_MAX];
    for (int i = t; i < NPART; i += 256) lh[i] = 0;
    __syncthreads();
    int chunk = (E + NBLK1 - 1) / NBLK1;
    int e0 = bid * chunk;
    int e1 = e0 + chunk; if (e1 > E) e1 = E;
    for (int e = e0 + t; e < e1; e += 256)
      atomicAdd(&lh[dstA[e] >> PSH], 1u);
    __syncthreads();
    for (int i = t; i < NPART; i += 256)
      pcnt[(size_t)bid * NPART_MAX + i] = lh[i];
  } else {
    // ---- transpose3: 2 virtual rows per block ----
    int vb = bid * 2 + (t >> 7);
    int c = t & 127;
    if (vb < 384)      w_ihT[(size_t)c * 384 + vb]         = w_ih[(size_t)vb * 128 + c];
    else if (vb < 768) w_hhT[(size_t)c * 384 + (vb - 384)] = w_hh[(size_t)(vb - 384) * 128 + c];
    else               wlb[(size_t)(vb - 768) * 128 + c]   = f32_to_bf16(w_lin[(size_t)(vb - 768) * 128 + c]);
  }
}

// ============ L2: find_thresh || scan_blocks (1024 thr) ============
// scan_blocks: wave-shfl inclusive scan; pcnt read transposed (block-major).
__global__ __launch_bounds__(1024)
void k_mid1(const unsigned* __restrict__ hist, unsigned* __restrict__ Bthr,
            const unsigned* __restrict__ pcnt, unsigned* __restrict__ basel,
            unsigned* __restrict__ ptot)
{
  int t = threadIdx.x;
  if (blockIdx.x == 0) {
    // ---- find_thresh ----
    __shared__ unsigned part[1024];
    unsigned s = 0;
    for (int i = 0; i < 64; i++) s += hist[t * 64 + i];
    part[t] = s;
    __syncthreads();
    if (t == 0) {
      unsigned cum = 0;
      int chunk = 1023;
      for (; chunk >= 0; chunk--) {
        if (cum + part[chunk] >= 128u) break;
        cum += part[chunk];
      }
      unsigned B = 0;
      if (chunk >= 0) {
        int b = chunk * 64 + 63;
        for (; b >= chunk * 64; b--) {
          cum += hist[b];
          if (cum >= 128u) break;
        }
        B = (unsigned)b;
      }
      *Bthr = B;
    }
  } else {
    // ---- scan_blocks: wave-shfl scan over 1024 entries ----
    __shared__ unsigned wtot[16];
    int p = blockIdx.x - 1;
    int lane = t & 63, wv = t >> 6;
    unsigned c = pcnt[(size_t)t * NPART_MAX + p];
    unsigned v = c;
    #pragma unroll
    for (int d = 1; d < 64; d <<= 1) {
      unsigned u = __shfl_up(v, d, 64);
      if (lane >= d) v += u;
    }
    if (lane == 63) wtot[wv] = v;
    __syncthreads();
    unsigned add = 0;
    #pragma unroll
    for (int w = 0; w < 16; w++) if (w < wv) add += wtot[w];
    v += add;
    basel[(size_t)p * NBLK1 + t] = v - c;
    if (t == NBLK1 - 1) ptot[p] = v;
  }
}

// ============ L3: part_place || compact (512 thr) ============
// part_place: wave-shfl double scan (lcnt + ptot) -> poff in-block; pbuf
// records partition at bucket time -> direct-lookup write-out.
__global__ __launch_bounds__(512)
void k_mid2(const int* __restrict__ srcA, const int* __restrict__ dstA,
            const float* __restrict__ ew, const unsigned* __restrict__ ptot,
            const unsigned* __restrict__ basel, unsigned long long* __restrict__ epk2,
            int E, int NPART,
            const double* __restrict__ dvals, const unsigned* __restrict__ Bthr,
            unsigned long long* __restrict__ ckey, unsigned* __restrict__ cidx,
            unsigned* __restrict__ cnt, int N)
{
  int t = threadIdx.x;
  if (blockIdx.x < NBLK1) {
    // ---- part_place ----
    __shared__ unsigned long long ebuf[EBUF_MAX];
    __shared__ unsigned short pbuf[EBUF_MAX];
    __shared__ unsigned lcnt[NPART_MAX];
    __shared__ unsigned lbase[NPART_MAX];
    __shared__ unsigned cur[NPART_MAX];
    __shared__ int gbase[NPART_MAX];
    __shared__ unsigned wt1[8], wt2[8];
    int b = blockIdx.x;
    int chunk = (E + NBLK1 - 1) / NBLK1;
    int e0 = b * chunk;
    int e1 = e0 + chunk; if (e1 > E) e1 = E;
    int n = e1 - e0;

    lcnt[t] = 0;
    unsigned pt = (t < NPART) ? ptot[t] : 0u;
    __syncthreads();
    for (int e = e0 + t; e < e1; e += 512)
      atomicAdd(&lcnt[dstA[e] >> PSH], 1u);
    __syncthreads();
    int lane = t & 63, wv = t >> 6;
    unsigned c1 = lcnt[t];
    unsigned v1 = c1, v2 = pt;
    #pragma unroll
    for (int d = 1; d < 64; d <<= 1) {
      unsigned u1 = __shfl_up(v1, d, 64);
      unsigned u2 = __shfl_up(v2, d, 64);
      if (lane >= d) { v1 += u1; v2 += u2; }
    }
    if (lane == 63) { wt1[wv] = v1; wt2[wv] = v2; }
    __syncthreads();
    unsigned a1 = 0, a2 = 0;
    #pragma unroll
    for (int w = 0; w < 8; w++) if (w < wv) { a1 += wt1[w]; a2 += wt2[w]; }
    v1 += a1; v2 += a2;
    lbase[t] = v1 - c1;
    cur[t] = v1 - c1;
    gbase[t] = (t < NPART) ? ((int)(v2 - pt) + (int)basel[(size_t)t * NBLK1 + b]) : 0;
    __syncthreads();
    for (int e = e0 + t; e < e1; e += 512) {
      int d = dstA[e];
      int s = srcA[e];
      float w = ew[e];
      int p = d >> PSH;
      unsigned long long v = ((unsigned long long)__float_as_uint(w) << 32)
                           | ((unsigned long long)(unsigned)s << 8)
                           | (unsigned long long)(d & 255);
      unsigned pos = atomicAdd(&cur[p], 1u);
      ebuf[pos] = v;
      pbuf[pos] = (unsigned short)p;
    }
    __syncthreads();
    for (int j = t; j < n; j += 512) {
      int p = pbuf[j];
      epk2[gbase[p] + (j - (int)lbase[p])] = ebuf[j];
    }
  } else {
    // ---- compact: candidates with bin >= B ----
    int i = (blockIdx.x - NBLK1) * 512 + t;
    if (i >= N) return;
    unsigned B = *Bthr;
    double d = dvals[i];
    unsigned u = mono32((float)d);
    if ((u >> 16) >= B) {
      unsigned pos = atomicAdd(cnt, 1u);
      if (pos < CAP) {
        ckey[pos] = ~mono64(d);
        cidx[pos] = (unsigned)i;
      }
    }
  }
}

// ============ L4: topk_sort || part_csr (512 thr) ============
// part_csr: wave-shfl rsum reduce + wave-shfl 256-entry scan.
__global__ __launch_bounds__(512)
void k_mid3(const double* __restrict__ dvals, const float* __restrict__ pvec,
            const unsigned* __restrict__ cnt,
            const unsigned long long* __restrict__ ckey, const unsigned* __restrict__ cidx,
            unsigned* __restrict__ sel_idx, float* __restrict__ sel_ts,
            const unsigned* __restrict__ ptot, const unsigned long long* __restrict__ epk2,
            EdgeP* __restrict__ epk_out, int* __restrict__ off,
            float* __restrict__ dinv, int N, int NPART)
{
  int t = threadIdx.x;
  if (blockIdx.x == 0) {
    // ---- topk_sort (512-thread bitonic) ----
    __shared__ unsigned long long k[CAP];
    __shared__ unsigned id[CAP];
    __shared__ double red[128];
    __shared__ double pn_sh;
    unsigned C = *cnt;
    if (C > CAP) C = CAP;
    int S = 128;
    while (S < (int)C) S <<= 1;
    for (int i = t; i < S; i += 512) {
      if (i < (int)C) { k[i] = ckey[i]; id[i] = cidx[i]; }
      else            { k[i] = ~0ULL;   id[i] = 0xFFFFFFFFu; }
    }
    __syncthreads();
    for (int kk = 2; kk <= S; kk <<= 1) {
      for (int j = kk >> 1; j > 0; j >>= 1) {
        for (int i = t; i < S; i += 512) {
          int q = i ^ j;
          if (q > i) {
            bool up = ((i & kk) == 0);
            bool g = (k[i] > k[q]) || (k[i] == k[q] && id[i] > id[q]);
            if (g == up) {
              unsigned long long tk = k[i]; k[i] = k[q]; k[q] = tk;
              unsigned ti = id[i]; id[i] = id[q]; id[q] = ti;
            }
          }
        }
        __syncthreads();
      }
    }
    if (t < 128) { double v = (double)pvec[t]; red[t] = v * v; }
    __syncthreads();
    if (t == 0) {
      double s = 0.0;
      for (int i = 0; i < 128; i++) s += red[i];
      pn_sh = sqrt(s);
    }
    __syncthreads();
    if (t < 128) {
      unsigned n = id[t];
      sel_idx[t] = n;
      sel_ts[t] = (float)tanh(dvals[n] / pn_sh);
    }
  } else {
    // ---- part_csr ----
    int p = blockIdx.x - 1;
    int lane = t & 63, wv = t >> 6;
    __shared__ unsigned ws[8];
    __shared__ unsigned wt[4];
    __shared__ unsigned lcnt[256];
    __shared__ float ldeg[256];
    // beg = sum of ptot[0..p-1] via wave reduce (p < 512)
    unsigned a = (t < p) ? ptot[t] : 0u;
    #pragma unroll
    for (int d = 32; d > 0; d >>= 1) a += __shfl_xor(a, d, 64);
    if (lane == 0) ws[wv] = a;
    __syncthreads();
    unsigned bu = 0;
    #pragma unroll
    for (int w = 0; w < 8; w++) bu += ws[w];
    int beg = (int)bu;
    int end = beg + (int)ptot[p];

    int n0 = p << PSH;
    int nn = N - n0; if (nn > 256) nn = 256;
    if (t < 256) { lcnt[t] = 0; ldeg[t] = 0.f; }
    __syncthreads();
    for (int i = beg + t; i < end; i += 512) {
      unsigned long long v = epk2[i];
      int ln = (int)(v & 255u);
      float w = __uint_as_float((unsigned)(v >> 32));
      atomicAdd(&lcnt[ln], 1u);
      atomicAdd(&ldeg[ln], w);
    }
    __syncthreads();
    unsigned c = 0, v = 0;
    if (t < 256) {
      c = lcnt[t]; v = c;
      #pragma unroll
      for (int d = 1; d < 64; d <<= 1) {
        unsigned u = __shfl_up(v, d, 64);
        if (lane >= d) v += u;
      }
    }
    if (t < 256 && lane == 63) wt[wv] = v;
    __syncthreads();
    unsigned excl = 0;
    if (t < 256) {
      unsigned add = 0;
      #pragma unroll
      for (int w = 0; w < 4; w++) if (w < wv) add += wt[w];
      v += add;
      excl = v - c;
    }
    if (t < nn) {
      off[n0 + t] = beg + (int)excl;
      dinv[n0 + t] = rsqrtf(ldeg[t] + 1.0f);  // +1 = self loop
    }
    if (p == NPART - 1 && t == 0) off[N] = end;
    if (t < 256) lcnt[t] = excl;  // reuse as running cursor
    __syncthreads();
    for (int i = beg + t; i < end; i += 512) {
      unsigned long long vv = epk2[i];
      int ln = (int)(vv & 255u);
      unsigned q = atomicAdd(&lcnt[ln], 1u);
      EdgeP ep;
      ep.s = (int)((vv >> 8) & 0xFFFFFFu);
      ep.w = __uint_as_float((unsigned)(vv >> 32));
      epk_out[beg + (int)q] = ep;
    }
  }
}

// ============ L5: gru_evolve || csr_gather4 (256 thr, unified launch) ============
// gather: 4-deep batching (16 edges/step) — measured TLP optimum (round 7).
__global__ __launch_bounds__(256)
void k_gg(const float* __restrict__ x, const unsigned* __restrict__ sel_idx,
          const float* __restrict__ sel_ts,
          const float* __restrict__ w_ihT, const float* __restrict__ w_hhT,
          const float* __restrict__ b_ih, const float* __restrict__ b_hh,
          const float* __restrict__ w0, unsigned short* __restrict__ WbT,
          const int* __restrict__ off, const EdgeP* __restrict__ epk,
          const float* __restrict__ dinv, const unsigned short* __restrict__ xb,
          unsigned short* __restrict__ aggb, int N)
{
  int t = threadIdx.x;
  if (blockIdx.x < 128) {
    // ---- gru_evolve (256 thr): thread t handles gate cols t and 256+t(<384) ----
    __shared__ float xt[FD], w0r[FD];
    __shared__ float gi[384], gh[384];
    int i = blockIdx.x;
    if (t < FD) {
      unsigned n = sel_idx[i];
      float ts = sel_ts[i];
      xt[t]  = x[(size_t)n * FD + t] * ts;
      w0r[t] = w0[i * FD + t];
    }
    __syncthreads();
    bool has2 = t < 128;
    float ga0 = b_ih[t], ha0 = b_hh[t];
    float ga1 = 0.f, ha1 = 0.f;
    if (has2) { ga1 = b_ih[256 + t]; ha1 = b_hh[256 + t]; }
    for (int kx = 0; kx < FD; kx++) {
      float xv = xt[kx], hv = w0r[kx];
      const float* wi = w_ihT + (size_t)kx * 384;
      const float* wh = w_hhT + (size_t)kx * 384;
      ga0 += xv * wi[t];
      ha0 += hv * wh[t];
      if (has2) {
        ga1 += xv * wi[256 + t];
        ha1 += hv * wh[256 + t];
      }
    }
    gi[t] = ga0; gh[t] = ha0;
    if (has2) { gi[256 + t] = ga1; gh[256 + t] = ha1; }
    __syncthreads();
    if (t < FD) {
      float r = 1.f / (1.f + expf(-(gi[t] + gh[t])));
      float z = 1.f / (1.f + expf(-(gi[128 + t] + gh[128 + t])));
      float nn = tanhf(gi[256 + t] + r * gh[256 + t]);
      float wv = (1.f - z) * nn + z * w0r[t];
      WbT[(size_t)t * FD + i] = f32_to_bf16(wv);
    }
  } else {
    // ---- csr_gather4: 4-deep (16 edges/step), group-uniform edge loads ----
    int gid = (blockIdx.x - 128) * 256 + t;
    int wid = gid >> 6, lane = t & 63;
    if (wid >= N) return;
    int g = lane >> 4, sub = lane & 15;
    int n = wid;
    int beg = off[n], end = off[n + 1];
    int cnt = end - beg;
    const EdgeP* ep_base = epk + beg;

    float di = dinv[n];
    uint4 xs4 = *(const uint4*)(xb + (size_t)n * FD + sub * 8);

    float acc[8];
    #pragma unroll
    for (int j = 0; j < 8; j++) acc[j] = 0.f;

    int nfull = cnt >> 4;
    int base = 0;
    for (int s16 = 0; s16 < nfull; s16++, base += 16) {
      uint2 ep[4];
      #pragma unroll
      for (int u = 0; u < 4; u++)
        ep[u] = *(const uint2*)(ep_base + base + u * 4 + g);
      float dv[4]; uint4 pv[4];
      #pragma unroll
      for (int u = 0; u < 4; u++) {
        int s = (int)ep[u].x;
        dv[u] = dinv[s];
        pv[u] = *(const uint4*)(xb + (size_t)s * FD + sub * 8);
      }
      #pragma unroll
      for (int u = 0; u < 4; u++) {
        float w = __uint_as_float(ep[u].y) * dv[u];
        acc[0] = fmaf(f16lo(pv[u].x), w, acc[0]); acc[1] = fmaf(f16hi(pv[u].x), w, acc[1]);
        acc[2] = fmaf(f16lo(pv[u].y), w, acc[2]); acc[3] = fmaf(f16hi(pv[u].y), w, acc[3]);
        acc[4] = fmaf(f16lo(pv[u].z), w, acc[4]); acc[5] = fmaf(f16hi(pv[u].z), w, acc[5]);
        acc[6] = fmaf(f16lo(pv[u].w), w, acc[6]); acc[7] = fmaf(f16hi(pv[u].w), w, acc[7]);
      }
    }
    if (base < cnt) {
      int last = cnt - 1;
      uint2 ep[4];
      #pragma unroll
      for (int u = 0; u < 4; u++) {
        int idx = base + u * 4 + g;
        int idc = idx < cnt ? idx : last;
        ep[u] = *(const uint2*)(ep_base + idc);
      }
      float dv[4]; uint4 pv[4];
      #pragma unroll
      for (int u = 0; u < 4; u++) {
        int s = (int)ep[u].x;
        dv[u] = dinv[s];
        pv[u] = *(const uint4*)(xb + (size_t)s * FD + sub * 8);
      }
      #pragma unroll
      for (int u = 0; u < 4; u++) {
        int idx = base + u * 4 + g;
        float w = (idx < cnt) ? __uint_as_float(ep[u].y) * dv[u] : 0.f;
        acc[0] = fmaf(f16lo(pv[u].x), w, acc[0]); acc[1] = fmaf(f16hi(pv[u].x), w, acc[1]);
        acc[2] = fmaf(f16lo(pv[u].y), w, acc[2]); acc[3] = fmaf(f16hi(pv[u].y), w, acc[3]);
        acc[4] = fmaf(f16lo(pv[u].z), w, acc[4]); acc[5] = fmaf(f16hi(pv[u].z), w, acc[5]);
        acc[6] = fmaf(f16lo(pv[u].w), w, acc[6]); acc[7] = fmaf(f16hi(pv[u].w), w, acc[7]);
      }
    }

    #pragma unroll
    for (int j = 0; j < 8; j++) {
      acc[j] += __shfl_xor(acc[j], 16, 64);
      acc[j] += __shfl_xor(acc[j], 32, 64);
    }
    if (g == 0) {
      float dii = di * di;
      uint4 o;
      o.x = pack_bf16(di * acc[0] + dii * f16lo(xs4.x), di * acc[1] + dii * f16hi(xs4.x));
      o.y = pack_bf16(di * acc[2] + dii * f16lo(xs4.y), di * acc[3] + dii * f16hi(xs4.y));
      o.z = pack_bf16(di * acc[4] + dii * f16lo(xs4.z), di * acc[5] + dii * f16hi(xs4.z));
      o.w = pack_bf16(di * acc[6] + dii * f16lo(xs4.w), di * acc[7] + dii * f16hi(xs4.w));
      *(uint4*)(aggb + (size_t)n * FD + sub * 8) = o;
    }
  }
}

// ---- MFMA epilogue: out = relu(aggb·W)·w_lin^T + b ----
__global__ __launch_bounds__(256)
void gemm_mfma(const unsigned short* __restrict__ aggb, const unsigned short* __restrict__ WbT,
               const unsigned short* __restrict__ wlb, const float* __restrict__ bias,
               float* __restrict__ C, int nrows)
{
  __shared__ unsigned short hs[64][136];  // +8 bf16 pad: 272B row stride
  int tid = threadIdx.x;
  int wv = tid >> 6, lane = tid & 63;
  int row16 = lane & 15;
  int kgrp = lane >> 4;
  int r0 = blockIdx.x * 64;
  int arow = r0 + wv * 16 + row16;
  bool rowok = arow < nrows;

  f32x4 acc[8];
  #pragma unroll
  for (int t = 0; t < 8; t++) acc[t] = (f32x4){0.f, 0.f, 0.f, 0.f};

  #pragma unroll
  for (int ks = 0; ks < 4; ks++) {
    int k = ks * 32 + kgrp * 8;
    bf16x8 a;
    if (rowok) a = *(const bf16x8*)(aggb + (size_t)arow * FD + k);
    else       a = (bf16x8){0, 0, 0, 0, 0, 0, 0, 0};
    #pragma unroll
    for (int t = 0; t < 8; t++) {
      int col = t * 16 + row16;
      bf16x8 b = *(const bf16x8*)(WbT + (size_t)col * FD + k);
      acc[t] = __builtin_amdgcn_mfma_f32_16x16x32_bf16(a, b, acc[t], 0, 0, 0);
    }
  }
  #pragma unroll
  for (int t = 0; t < 8; t++) {
    int col = t * 16 + row16;
    #pragma unroll
    for (int r = 0; r < 4; r++) {
      int row_l = wv * 16 + kgrp * 4 + r;
      hs[row_l][col] = f32_to_bf16(fmaxf(acc[t][r], 0.f));
    }
  }
  __syncthreads();

  f32x4 acc2[8];
  #pragma unroll
  for (int t = 0; t < 8; t++) acc2[t] = (f32x4){0.f, 0.f, 0.f, 0.f};
  #pragma unroll
  for (int ks = 0; ks < 4; ks++) {
    int k = ks * 32 + kgrp * 8;
    bf16x8 a = *(const bf16x8*)(&hs[wv * 16 + row16][k]);
    #pragma unroll
    for (int t = 0; t < 8; t++) {
      int col = t * 16 + row16;
      bf16x8 b = *(const bf16x8*)(wlb + (size_t)col * FD + k);
      acc2[t] = __builtin_amdgcn_mfma_f32_16x16x32_bf16(a, b, acc2[t], 0, 0, 0);
    }
  }
  #pragma unroll
  for (int t = 0; t < 8; t++) {
    int col = t * 16 + row16;
    float bl = bias[col];
    #pragma unroll
    for (int r = 0; r < 4; r++) {
      int row = r0 + wv * 16 + kgrp * 4 + r;
      if (row < nrows) C[(size_t)row * FD + col] = acc2[t][r] + bl;
    }
  }
}

extern "C" void kernel_launch(void* const* d_in, const int* in_sizes, int n_in,
                              void* d_out, int out_size, void* d_ws, size_t ws_size,
                              hipStream_t stream)
{
  const float* x     = (const float*)d_in[0];
  const float* ew    = (const float*)d_in[1];
  const float* pvec  = (const float*)d_in[2];
  const float* w_ih  = (const float*)d_in[3];
  const float* w_hh  = (const float*)d_in[4];
  const float* b_ih  = (const float*)d_in[5];
  const float* b_hh  = (const float*)d_in[6];
  const float* w0    = (const float*)d_in[7];
  const float* w_lin = (const float*)d_in[8];
  const float* b_lin = (const float*)d_in[9];
  const int*   eidx  = (const int*)d_in[10];

  int N = in_sizes[0] / FD;
  int E = in_sizes[1];
  int NPART = (N + 255) >> PSH;
  const int* srcA = eidx;
  const int* dstA = eidx + E;

  char* base = (char*)d_ws;
  size_t off_ws = 0;
  auto take = [&](size_t bytes) -> void* {
    void* ptr = base + off_ws;
    off_ws = alignup256(off_ws + bytes);
    return ptr;
  };
  double* dvals = (double*)take((size_t)N * 8);
  unsigned* hist = (unsigned*)take(65536u * 4);
  unsigned* cnt = (unsigned*)take(4);
  unsigned* Bthr = (unsigned*)take(4);
  unsigned long long* ckey = (unsigned long long*)take((size_t)CAP * 8);
  unsigned* cidx = (unsigned*)take((size_t)CAP * 4);
  unsigned* sel_idx = (unsigned*)take(128 * 4);
  float* sel_ts = (float*)take(128 * 4);
  unsigned short* WbT = (unsigned short*)take(FD * FD * 2);
  unsigned short* wlb = (unsigned short*)take(FD * FD * 2);
  float* w_ihT = (float*)take(3 * FD * FD * 4);
  float* w_hhT = (float*)take(3 * FD * FD * 4);
  float* dinv = (float*)take((size_t)N * 4);
  unsigned* pcnt = (unsigned*)take((size_t)NPART_MAX * NBLK1 * 4);
  unsigned* basel = (unsigned*)take((size_t)NPART_MAX * NBLK1 * 4);
  unsigned* ptot = (unsigned*)take((size_t)NPART_MAX * 4);
  int* off = (int*)take(((size_t)N + 1) * 4);
  unsigned long long* epk2 = (unsigned long long*)take((size_t)E * 8);
  EdgeP* epk_b = (EdgeP*)take((size_t)E * 8);
  unsigned short* xb = (unsigned short*)take((size_t)N * FD * 2);
  unsigned short* aggb = (unsigned short*)take((size_t)N * FD * 2);
  float* out1 = (float*)d_out;

  hipMemsetAsync(hist, 0, 65536u * 4, stream);

  // L1: score_pack || part_count || transpose3 (interleaved branches)
  k_front<<<SCORE_BLKS + NBLK1 + TRANS_BLKS, 256, 0, stream>>>(
      x, pvec, dvals, hist, xb, cnt, N, dstA, pcnt, E, NPART,
      w_ih, w_hh, w_lin, w_ihT, w_hhT, wlb);
  // L2: find_thresh || scan_blocks
  k_mid1<<<1 + NPART, 1024, 0, stream>>>(hist, Bthr, pcnt, basel, ptot);
  // L3: part_place || compact
  k_mid2<<<NBLK1 + (N + 511) / 512, 512, 0, stream>>>(
      srcA, dstA, ew, ptot, basel, epk2, E, NPART,
      dvals, Bthr, ckey, cidx, cnt, N);
  // L4: topk_sort || part_csr
  k_mid3<<<1 + NPART, 512, 0, stream>>>(
      dvals, pvec, cnt, ckey, cidx, sel_idx, sel_ts,
      ptot, epk2, epk_b, off, dinv, N, NPART);
  // L5: gru_evolve || csr_gather4 (unified)
  k_gg<<<128 + (N * 64 + 255) / 256, 256, 0, stream>>>(
      x, sel_idx, sel_ts, w_ihT, w_hhT, b_ih, b_hh, w0, WbT,
      off, epk_b, dinv, xb, aggb, N);
  // L6: MFMA epilogue
  gemm_mfma<<<(N + 63) / 64, 256, 0, stream>>>(aggb, WbT, wlb, b_lin, out1, N);
}

// Round 11
// 351.055 us; speedup vs baseline: 1.0921x; 1.0024x over previous
//
#include <hip/hip_runtime.h>
#include <hip/hip_fp16.h>
#include <stdint.h>

#define FD 128
#define CAP 4096
#define PSH 8                 // 256 nodes per partition
#define NPART_MAX 512
#define NBLK1 1024            // build blocks; chunk = ceil(E/NBLK1) <= EBUF_MAX
#define EBUF_MAX 3136         // chunk=3125 at E=3.2M; 39.6KB LDS -> 4 blocks/CU
#define SCORE_BLKS 2048
#define TRANS_BLKS 448        // 896 virtual rows, 2 per block
#define CSR_CACHE 18          // 18*512 = 9216 >= partition size (+11 sigma)

static inline size_t alignup256(size_t x) { return (x + 255) & ~(size_t)255; }

struct EdgeP { int s; float w; };

typedef __attribute__((ext_vector_type(4))) float f32x4;
typedef __attribute__((ext_vector_type(8))) short bf16x8;

__device__ __forceinline__ unsigned short f32_to_bf16(float f) {
  unsigned u = __float_as_uint(f);
  u += 0x7fffu + ((u >> 16) & 1u);
  return (unsigned short)(u >> 16);
}
__device__ __forceinline__ unsigned pack_bf16(float a, float b) {
  return ((unsigned)f32_to_bf16(b) << 16) | (unsigned)f32_to_bf16(a);
}
// f16 payload for xb: consume side fuses cvt+fma into v_fma_mix_f32.
__device__ __forceinline__ unsigned pack_f16(float a, float b) {
  unsigned short ha = __half_as_ushort(__float2half_rn(a));
  unsigned short hb = __half_as_ushort(__float2half_rn(b));
  return ((unsigned)hb << 16) | (unsigned)ha;
}
__device__ __forceinline__ float f16lo(unsigned u) {
  return __half2float(__ushort_as_half((unsigned short)(u & 0xffffu)));
}
__device__ __forceinline__ float f16hi(unsigned u) {
  return __half2float(__ushort_as_half((unsigned short)(u >> 16)));
}
__device__ __forceinline__ unsigned mono32(float f) {
  unsigned u = __float_as_uint(f);
  return (u & 0x80000000u) ? ~u : (u | 0x80000000u);
}
__device__ __forceinline__ unsigned long long mono64(double d) {
  unsigned long long b = (unsigned long long)__double_as_longlong(d);
  return (b & 0x8000000000000000ULL) ? ~b : (b | 0x8000000000000000ULL);
}

// ============ L1: score_pack || part_count || transpose3 (256 thr) ============
// Branch interleave: blocks 0..2047 alternate score/count so both phases
// co-reside. score is 4-deep unrolled (4 independent dot-chains in flight).
// pcnt stored block-major (coalesced, no strided RMW).
__global__ __launch_bounds__(256)
void k_front(const float* __restrict__ x, const float* __restrict__ pvec,
             double* __restrict__ dvals, unsigned* __restrict__ hist,
             unsigned short* __restrict__ xb, unsigned* __restrict__ cnt, int N,
             const int* __restrict__ dstA, unsigned* __restrict__ pcnt, int E, int NPART,
             const float* __restrict__ w_ih, const float* __restrict__ w_hh,
             const float* __restrict__ w_lin, float* __restrict__ w_ihT,
             float* __restrict__ w_hhT, unsigned short* __restrict__ wlb)
{
  int b = blockIdx.x, t = threadIdx.x;
  int branch, bid;
  if (b < 2 * NBLK1)            { branch = (b & 1); bid = b >> 1; }
  else if (b < SCORE_BLKS + NBLK1) { branch = 0; bid = NBLK1 + (b - 2 * NBLK1); }
  else                          { branch = 2; bid = b - (SCORE_BLKS + NBLK1); }

  if (branch == 0) {
    // ---- score_pack: f64 dot(x_row, p) + f16 pack of x, 4-deep unroll ----
    int gid = bid * 256 + t;
    if (gid == 0) *cnt = 0u;
    int wid = gid >> 6, lane = t & 63;
    const int nw = (SCORE_BLKS * 256) >> 6;
    double p0 = (double)pvec[lane * 2], p1 = (double)pvec[lane * 2 + 1];
    for (int n0 = wid; n0 < N; n0 += 4 * nw) {
      int ns[4]; bool ok[4];
      float2 xv[4];
      #pragma unroll
      for (int u = 0; u < 4; u++) {
        ns[u] = n0 + u * nw;
        ok[u] = ns[u] < N;
        xv[u] = make_float2(0.f, 0.f);
        if (ok[u]) xv[u] = *(const float2*)(x + (size_t)ns[u] * FD + lane * 2);
      }
      #pragma unroll
      for (int u = 0; u < 4; u++)
        if (ok[u]) *(unsigned*)(xb + (size_t)ns[u] * FD + lane * 2) = pack_f16(xv[u].x, xv[u].y);
      double s[4];
      #pragma unroll
      for (int u = 0; u < 4; u++) s[u] = (double)xv[u].x * p0 + (double)xv[u].y * p1;
      #pragma unroll
      for (int o = 32; o > 0; o >>= 1) {
        #pragma unroll
        for (int u = 0; u < 4; u++) s[u] += __shfl_down(s[u], o, 64);
      }
      if (lane == 0) {
        #pragma unroll
        for (int u = 0; u < 4; u++) {
          if (ok[u]) {
            dvals[ns[u]] = s[u];
            atomicAdd(&hist[mono32((float)s[u]) >> 16], 1u);
          }
        }
      }
    }
  } else if (branch == 1) {
    // ---- part_count: per-(block, partition) counts, block-major store ----
    __shared__ unsigned lh[NPART_MAX];
    for (int i = t; i < NPART; i += 256) lh[i] = 0;
    __syncthreads();
    int chunk = (E + NBLK1 - 1) / NBLK1;
    int e0 = bid * chunk;
    int e1 = e0 + chunk; if (e1 > E) e1 = E;
    for (int e = e0 + t; e < e1; e += 256)
      atomicAdd(&lh[dstA[e] >> PSH], 1u);
    __syncthreads();
    for (int i = t; i < NPART; i += 256)
      pcnt[(size_t)bid * NPART_MAX + i] = lh[i];
  } else {
    // ---- transpose3: 2 virtual rows per block ----
    int vb = bid * 2 + (t >> 7);
    int c = t & 127;
    if (vb < 384)      w_ihT[(size_t)c * 384 + vb]         = w_ih[(size_t)vb * 128 + c];
    else if (vb < 768) w_hhT[(size_t)c * 384 + (vb - 384)] = w_hh[(size_t)(vb - 384) * 128 + c];
    else               wlb[(size_t)(vb - 768) * 128 + c]   = f32_to_bf16(w_lin[(size_t)(vb - 768) * 128 + c]);
  }
}

// ============ L2: find_thresh || scan_blocks (1024 thr) ============
// scan_blocks: wave-shfl inclusive scan; pcnt read transposed (block-major).
__global__ __launch_bounds__(1024)
void k_mid1(const unsigned* __restrict__ hist, unsigned* __restrict__ Bthr,
            const unsigned* __restrict__ pcnt, unsigned* __restrict__ basel,
            unsigned* __restrict__ ptot)
{
  int t = threadIdx.x;
  if (blockIdx.x == 0) {
    // ---- find_thresh ----
    __shared__ unsigned part[1024];
    unsigned s = 0;
    for (int i = 0; i < 64; i++) s += hist[t * 64 + i];
    part[t] = s;
    __syncthreads();
    if (t == 0) {
      unsigned cum = 0;
      int chunk = 1023;
      for (; chunk >= 0; chunk--) {
        if (cum + part[chunk] >= 128u) break;
        cum += part[chunk];
      }
      unsigned B = 0;
      if (chunk >= 0) {
        int b = chunk * 64 + 63;
        for (; b >= chunk * 64; b--) {
          cum += hist[b];
          if (cum >= 128u) break;
        }
        B = (unsigned)b;
      }
      *Bthr = B;
    }
  } else {
    // ---- scan_blocks: wave-shfl scan over 1024 entries ----
    __shared__ unsigned wtot[16];
    int p = blockIdx.x - 1;
    int lane = t & 63, wv = t >> 6;
    unsigned c = pcnt[(size_t)t * NPART_MAX + p];
    unsigned v = c;
    #pragma unroll
    for (int d = 1; d < 64; d <<= 1) {
      unsigned u = __shfl_up(v, d, 64);
      if (lane >= d) v += u;
    }
    if (lane == 63) wtot[wv] = v;
    __syncthreads();
    unsigned add = 0;
    #pragma unroll
    for (int w = 0; w < 16; w++) if (w < wv) add += wtot[w];
    v += add;
    basel[(size_t)p * NBLK1 + t] = v - c;
    if (t == NBLK1 - 1) ptot[p] = v;
  }
}

// ============ L3: part_place || compact (512 thr) ============
// part_place: wave-shfl double scan (lcnt + ptot) -> poff in-block; pbuf
// records partition at bucket time -> direct-lookup write-out.
// EBUF shrunk to 3136 (chunk=3125): LDS 39.6KB -> 4 blocks/CU (was 3).
__global__ __launch_bounds__(512)
void k_mid2(const int* __restrict__ srcA, const int* __restrict__ dstA,
            const float* __restrict__ ew, const unsigned* __restrict__ ptot,
            const unsigned* __restrict__ basel, unsigned long long* __restrict__ epk2,
            int E, int NPART,
            const double* __restrict__ dvals, const unsigned* __restrict__ Bthr,
            unsigned long long* __restrict__ ckey, unsigned* __restrict__ cidx,
            unsigned* __restrict__ cnt, int N)
{
  int t = threadIdx.x;
  if (blockIdx.x < NBLK1) {
    // ---- part_place ----
    __shared__ unsigned long long ebuf[EBUF_MAX];
    __shared__ unsigned short pbuf[EBUF_MAX];
    __shared__ unsigned lcnt[NPART_MAX];
    __shared__ unsigned lbase[NPART_MAX];
    __shared__ unsigned cur[NPART_MAX];
    __shared__ int gbase[NPART_MAX];
    __shared__ unsigned wt1[8], wt2[8];
    int b = blockIdx.x;
    int chunk = (E + NBLK1 - 1) / NBLK1;
    int e0 = b * chunk;
    int e1 = e0 + chunk; if (e1 > E) e1 = E;
    int n = e1 - e0;

    lcnt[t] = 0;
    unsigned pt = (t < NPART) ? ptot[t] : 0u;
    __syncthreads();
    for (int e = e0 + t; e < e1; e += 512)
      atomicAdd(&lcnt[dstA[e] >> PSH], 1u);
    __syncthreads();
    int lane = t & 63, wv = t >> 6;
    unsigned c1 = lcnt[t];
    unsigned v1 = c1, v2 = pt;
    #pragma unroll
    for (int d = 1; d < 64; d <<= 1) {
      unsigned u1 = __shfl_up(v1, d, 64);
      unsigned u2 = __shfl_up(v2, d, 64);
      if (lane >= d) { v1 += u1; v2 += u2; }
    }
    if (lane == 63) { wt1[wv] = v1; wt2[wv] = v2; }
    __syncthreads();
    unsigned a1 = 0, a2 = 0;
    #pragma unroll
    for (int w = 0; w < 8; w++) if (w < wv) { a1 += wt1[w]; a2 += wt2[w]; }
    v1 += a1; v2 += a2;
    lbase[t] = v1 - c1;
    cur[t] = v1 - c1;
    gbase[t] = (t < NPART) ? ((int)(v2 - pt) + (int)basel[(size_t)t * NBLK1 + b]) : 0;
    __syncthreads();
    for (int e = e0 + t; e < e1; e += 512) {
      int d = dstA[e];
      int s = srcA[e];
      float w = ew[e];
      int p = d >> PSH;
      unsigned long long v = ((unsigned long long)__float_as_uint(w) << 32)
                           | ((unsigned long long)(unsigned)s << 8)
                           | (unsigned long long)(d & 255);
      unsigned pos = atomicAdd(&cur[p], 1u);
      ebuf[pos] = v;
      pbuf[pos] = (unsigned short)p;
    }
    __syncthreads();
    for (int j = t; j < n; j += 512) {
      int p = pbuf[j];
      epk2[gbase[p] + (j - (int)lbase[p])] = ebuf[j];
    }
  } else {
    // ---- compact: candidates with bin >= B ----
    int i = (blockIdx.x - NBLK1) * 512 + t;
    if (i >= N) return;
    unsigned B = *Bthr;
    double d = dvals[i];
    unsigned u = mono32((float)d);
    if ((u >> 16) >= B) {
      unsigned pos = atomicAdd(cnt, 1u);
      if (pos < CAP) {
        ckey[pos] = ~mono64(d);
        cidx[pos] = (unsigned)i;
      }
    }
  }
}

// ============ L4: topk_sort || part_csr (512 thr) ============
// part_csr: single-read — pass 1 caches edges in registers (fixed-trip
// unrolled loop -> compile-time indices -> stays in VGPRs, rule #20);
// pass 2 places from cache; overflow beyond 18*512 re-reads (correct, rare).
__global__ __launch_bounds__(512)
void k_mid3(const double* __restrict__ dvals, const float* __restrict__ pvec,
            const unsigned* __restrict__ cnt,
            const unsigned long long* __restrict__ ckey, const unsigned* __restrict__ cidx,
            unsigned* __restrict__ sel_idx, float* __restrict__ sel_ts,
            const unsigned* __restrict__ ptot, const unsigned long long* __restrict__ epk2,
            EdgeP* __restrict__ epk_out, int* __restrict__ off,
            float* __restrict__ dinv, int N, int NPART)
{
  int t = threadIdx.x;
  if (blockIdx.x == 0) {
    // ---- topk_sort (512-thread bitonic) ----
    __shared__ unsigned long long k[CAP];
    __shared__ unsigned id[CAP];
    __shared__ double red[128];
    __shared__ double pn_sh;
    unsigned C = *cnt;
    if (C > CAP) C = CAP;
    int S = 128;
    while (S < (int)C) S <<= 1;
    for (int i = t; i < S; i += 512) {
      if (i < (int)C) { k[i] = ckey[i]; id[i] = cidx[i]; }
      else            { k[i] = ~0ULL;   id[i] = 0xFFFFFFFFu; }
    }
    __syncthreads();
    for (int kk = 2; kk <= S; kk <<= 1) {
      for (int j = kk >> 1; j > 0; j >>= 1) {
        for (int i = t; i < S; i += 512) {
          int q = i ^ j;
          if (q > i) {
            bool up = ((i & kk) == 0);
            bool g = (k[i] > k[q]) || (k[i] == k[q] && id[i] > id[q]);
            if (g == up) {
              unsigned long long tk = k[i]; k[i] = k[q]; k[q] = tk;
              unsigned ti = id[i]; id[i] = id[q]; id[q] = ti;
            }
          }
        }
        __syncthreads();
      }
    }
    if (t < 128) { double v = (double)pvec[t]; red[t] = v * v; }
    __syncthreads();
    if (t == 0) {
      double s = 0.0;
      for (int i = 0; i < 128; i++) s += red[i];
      pn_sh = sqrt(s);
    }
    __syncthreads();
    if (t < 128) {
      unsigned n = id[t];
      sel_idx[t] = n;
      sel_ts[t] = (float)tanh(dvals[n] / pn_sh);
    }
  } else {
    // ---- part_csr (single-read, register cache) ----
    int p = blockIdx.x - 1;
    int lane = t & 63, wv = t >> 6;
    __shared__ unsigned ws[8];
    __shared__ unsigned wt[4];
    __shared__ unsigned lcnt[256];
    __shared__ float ldeg[256];
    // beg = sum of ptot[0..p-1] via wave reduce (p < 512)
    unsigned a = (t < p) ? ptot[t] : 0u;
    #pragma unroll
    for (int d = 32; d > 0; d >>= 1) a += __shfl_xor(a, d, 64);
    if (lane == 0) ws[wv] = a;
    __syncthreads();
    unsigned bu = 0;
    #pragma unroll
    for (int w = 0; w < 8; w++) bu += ws[w];
    int beg = (int)bu;
    int end = beg + (int)ptot[p];

    int n0 = p << PSH;
    int nn = N - n0; if (nn > 256) nn = 256;
    if (t < 256) { lcnt[t] = 0; ldeg[t] = 0.f; }
    __syncthreads();
    // pass 1: count + register cache
    unsigned long long cache[CSR_CACHE];
    {
      int i = beg + t;
      #pragma unroll
      for (int k = 0; k < CSR_CACHE; k++) {
        unsigned long long v = 0;
        if (i < end) {
          v = epk2[i];
          int ln = (int)(v & 255u);
          atomicAdd(&lcnt[ln], 1u);
          atomicAdd(&ldeg[ln], __uint_as_float((unsigned)(v >> 32)));
        }
        cache[k] = v;
        i += 512;
      }
      for (; i < end; i += 512) {   // overflow (rare; correct)
        unsigned long long v = epk2[i];
        int ln = (int)(v & 255u);
        atomicAdd(&lcnt[ln], 1u);
        atomicAdd(&ldeg[ln], __uint_as_float((unsigned)(v >> 32)));
      }
    }
    __syncthreads();
    unsigned c = 0, v = 0;
    if (t < 256) {
      c = lcnt[t]; v = c;
      #pragma unroll
      for (int d = 1; d < 64; d <<= 1) {
        unsigned u = __shfl_up(v, d, 64);
        if (lane >= d) v += u;
      }
    }
    if (t < 256 && lane == 63) wt[wv] = v;
    __syncthreads();
    unsigned excl = 0;
    if (t < 256) {
      unsigned add = 0;
      #pragma unroll
      for (int w = 0; w < 4; w++) if (w < wv) add += wt[w];
      v += add;
      excl = v - c;
    }
    if (t < nn) {
      off[n0 + t] = beg + (int)excl;
      dinv[n0 + t] = rsqrtf(ldeg[t] + 1.0f);  // +1 = self loop
    }
    if (p == NPART - 1 && t == 0) off[N] = end;
    if (t < 256) lcnt[t] = excl;  // reuse as running cursor
    __syncthreads();
    // pass 2: place from cache
    {
      int i = beg + t;
      #pragma unroll
      for (int k = 0; k < CSR_CACHE; k++) {
        if (i < end) {
          unsigned long long vv = cache[k];
          int ln = (int)(vv & 255u);
          unsigned q = atomicAdd(&lcnt[ln], 1u);
          EdgeP ep;
          ep.s = (int)((vv >> 8) & 0xFFFFFFu);
          ep.w = __uint_as_float((unsigned)(vv >> 32));
          epk_out[beg + (int)q] = ep;
        }
        i += 512;
      }
      for (; i < end; i += 512) {   // overflow (rare; correct)
        unsigned long long vv = epk2[i];
        int ln = (int)(vv & 255u);
        unsigned q = atomicAdd(&lcnt[ln], 1u);
        EdgeP ep;
        ep.s = (int)((vv >> 8) & 0xFFFFFFu);
        ep.w = __uint_as_float((unsigned)(vv >> 32));
        epk_out[beg + (int)q] = ep;
      }
    }
  }
}

// ============ L5: gru_evolve || csr_gather4 (256 thr, unified launch) ============
// gather: 4-deep batching (16 edges/step) — measured TLP optimum (round 7).
__global__ __launch_bounds__(256)
void k_gg(const float* __restrict__ x, const unsigned* __restrict__ sel_idx,
          const float* __restrict__ sel_ts,
          const float* __restrict__ w_ihT, const float* __restrict__ w_hhT,
          const float* __restrict__ b_ih, const float* __restrict__ b_hh,
          const float* __restrict__ w0, unsigned short* __restrict__ WbT,
          const int* __restrict__ off, const EdgeP* __restrict__ epk,
          const float* __restrict__ dinv, const unsigned short* __restrict__ xb,
          unsigned short* __restrict__ aggb, int N)
{
  int t = threadIdx.x;
  if (blockIdx.x < 128) {
    // ---- gru_evolve (256 thr): thread t handles gate cols t and 256+t(<384) ----
    __shared__ float xt[FD], w0r[FD];
    __shared__ float gi[384], gh[384];
    int i = blockIdx.x;
    if (t < FD) {
      unsigned n = sel_idx[i];
      float ts = sel_ts[i];
      xt[t]  = x[(size_t)n * FD + t] * ts;
      w0r[t] = w0[i * FD + t];
    }
    __syncthreads();
    bool has2 = t < 128;
    float ga0 = b_ih[t], ha0 = b_hh[t];
    float ga1 = 0.f, ha1 = 0.f;
    if (has2) { ga1 = b_ih[256 + t]; ha1 = b_hh[256 + t]; }
    for (int kx = 0; kx < FD; kx++) {
      float xv = xt[kx], hv = w0r[kx];
      const float* wi = w_ihT + (size_t)kx * 384;
      const float* wh = w_hhT + (size_t)kx * 384;
      ga0 += xv * wi[t];
      ha0 += hv * wh[t];
      if (has2) {
        ga1 += xv * wi[256 + t];
        ha1 += hv * wh[256 + t];
      }
    }
    gi[t] = ga0; gh[t] = ha0;
    if (has2) { gi[256 + t] = ga1; gh[256 + t] = ha1; }
    __syncthreads();
    if (t < FD) {
      float r = 1.f / (1.f + expf(-(gi[t] + gh[t])));
      float z = 1.f / (1.f + expf(-(gi[128 + t] + gh[128 + t])));
      float nn = tanhf(gi[256 + t] + r * gh[256 + t]);
      float wv = (1.f - z) * nn + z * w0r[t];
      WbT[(size_t)t * FD + i] = f32_to_bf16(wv);
    }
  } else {
    // ---- csr_gather4: 4-deep (16 edges/step), group-uniform edge loads ----
    int gid = (blockIdx.x - 128) * 256 + t;
    int wid = gid >> 6, lane = t & 63;
    if (wid >= N) return;
    int g = lane >> 4, sub = lane & 15;
    int n = wid;
    int beg = off[n], end = off[n + 1];
    int cnt = end - beg;
    const EdgeP* ep_base = epk + beg;

    float di = dinv[n];
    uint4 xs4 = *(const uint4*)(xb + (size_t)n * FD + sub * 8);

    float acc[8];
    #pragma unroll
    for (int j = 0; j < 8; j++) acc[j] = 0.f;

    int nfull = cnt >> 4;
    int base = 0;
    for (int s16 = 0; s16 < nfull; s16++, base += 16) {
      uint2 ep[4];
      #pragma unroll
      for (int u = 0; u < 4; u++)
        ep[u] = *(const uint2*)(ep_base + base + u * 4 + g);
      float dv[4]; uint4 pv[4];
      #pragma unroll
      for (int u = 0; u < 4; u++) {
        int s = (int)ep[u].x;
        dv[u] = dinv[s];
        pv[u] = *(const uint4*)(xb + (size_t)s * FD + sub * 8);
      }
      #pragma unroll
      for (int u = 0; u < 4; u++) {
        float w = __uint_as_float(ep[u].y) * dv[u];
        acc[0] = fmaf(f16lo(pv[u].x), w, acc[0]); acc[1] = fmaf(f16hi(pv[u].x), w, acc[1]);
        acc[2] = fmaf(f16lo(pv[u].y), w, acc[2]); acc[3] = fmaf(f16hi(pv[u].y), w, acc[3]);
        acc[4] = fmaf(f16lo(pv[u].z), w, acc[4]); acc[5] = fmaf(f16hi(pv[u].z), w, acc[5]);
        acc[6] = fmaf(f16lo(pv[u].w), w, acc[6]); acc[7] = fmaf(f16hi(pv[u].w), w, acc[7]);
      }
    }
    if (base < cnt) {
      int last = cnt - 1;
      uint2 ep[4];
      #pragma unroll
      for (int u = 0; u < 4; u++) {
        int idx = base + u * 4 + g;
        int idc = idx < cnt ? idx : last;
        ep[u] = *(const uint2*)(ep_base + idc);
      }
      float dv[4]; uint4 pv[4];
      #pragma unroll
      for (int u = 0; u < 4; u++) {
        int s = (int)ep[u].x;
        dv[u] = dinv[s];
        pv[u] = *(const uint4*)(xb + (size_t)s * FD + sub * 8);
      }
      #pragma unroll
      for (int u = 0; u < 4; u++) {
        int idx = base + u * 4 + g;
        float w = (idx < cnt) ? __uint_as_float(ep[u].y) * dv[u] : 0.f;
        acc[0] = fmaf(f16lo(pv[u].x), w, acc[0]); acc[1] = fmaf(f16hi(pv[u].x), w, acc[1]);
        acc[2] = fmaf(f16lo(pv[u].y), w, acc[2]); acc[3] = fmaf(f16hi(pv[u].y), w, acc[3]);
        acc[4] = fmaf(f16lo(pv[u].z), w, acc[4]); acc[5] = fmaf(f16hi(pv[u].z), w, acc[5]);
        acc[6] = fmaf(f16lo(pv[u].w), w, acc[6]); acc[7] = fmaf(f16hi(pv[u].w), w, acc[7]);
      }
    }

    #pragma unroll
    for (int j = 0; j < 8; j++) {
      acc[j] += __shfl_xor(acc[j], 16, 64);
      acc[j] += __shfl_xor(acc[j], 32, 64);
    }
    if (g == 0) {
      float dii = di * di;
      uint4 o;
      o.x = pack_bf16(di * acc[0] + dii * f16lo(xs4.x), di * acc[1] + dii * f16hi(xs4.x));
      o.y = pack_bf16(di * acc[2] + dii * f16lo(xs4.y), di * acc[3] + dii * f16hi(xs4.y));
      o.z = pack_bf16(di * acc[4] + dii * f16lo(xs4.z), di * acc[5] + dii * f16hi(xs4.z));
      o.w = pack_bf16(di * acc[6] + dii * f16lo(xs4.w), di * acc[7] + dii * f16hi(xs4.w));
      *(uint4*)(aggb + (size_t)n * FD + sub * 8) = o;
    }
  }
}

// ---- MFMA epilogue: out = relu(aggb·W)·w_lin^T + b ----
__global__ __launch_bounds__(256)
void gemm_mfma(const unsigned short* __restrict__ aggb, const unsigned short* __restrict__ WbT,
               const unsigned short* __restrict__ wlb, const float* __restrict__ bias,
               float* __restrict__ C, int nrows)
{
  __shared__ unsigned short hs[64][136];  // +8 bf16 pad: 272B row stride
  int tid = threadIdx.x;
  int wv = tid >> 6, lane = tid & 63;
  int row16 = lane & 15;
  int kgrp = lane >> 4;
  int r0 = blockIdx.x * 64;
  int arow = r0 + wv * 16 + row16;
  bool rowok = arow < nrows;

  f32x4 acc[8];
  #pragma unroll
  for (int t = 0; t < 8; t++) acc[t] = (f32x4){0.f, 0.f, 0.f, 0.f};

  #pragma unroll
  for (int ks = 0; ks < 4; ks++) {
    int k = ks * 32 + kgrp * 8;
    bf16x8 a;
    if (rowok) a = *(const bf16x8*)(aggb + (size_t)arow * FD + k);
    else       a = (bf16x8){0, 0, 0, 0, 0, 0, 0, 0};
    #pragma unroll
    for (int t = 0; t < 8; t++) {
      int col = t * 16 + row16;
      bf16x8 b = *(const bf16x8*)(WbT + (size_t)col * FD + k);
      acc[t] = __builtin_amdgcn_mfma_f32_16x16x32_bf16(a, b, acc[t], 0, 0, 0);
    }
  }
  #pragma unroll
  for (int t = 0; t < 8; t++) {
    int col = t * 16 + row16;
    #pragma unroll
    for (int r = 0; r < 4; r++) {
      int row_l = wv * 16 + kgrp * 4 + r;
      hs[row_l][col] = f32_to_bf16(fmaxf(acc[t][r], 0.f));
    }
  }
  __syncthreads();

  f32x4 acc2[8];
  #pragma unroll
  for (int t = 0; t < 8; t++) acc2[t] = (f32x4){0.f, 0.f, 0.f, 0.f};
  #pragma unroll
  for (int ks = 0; ks < 4; ks++) {
    int k = ks * 32 + kgrp * 8;
    bf16x8 a = *(const bf16x8*)(&hs[wv * 16 + row16][k]);
    #pragma unroll
    for (int t = 0; t < 8; t++) {
      int col = t * 16 + row16;
      bf16x8 b = *(const bf16x8*)(wlb + (size_t)col * FD + k);
      acc2[t] = __builtin_amdgcn_mfma_f32_16x16x32_bf16(a, b, acc2[t], 0, 0, 0);
    }
  }
  #pragma unroll
  for (int t = 0; t < 8; t++) {
    int col = t * 16 + row16;
    float bl = bias[col];
    #pragma unroll
    for (int r = 0; r < 4; r++) {
      int row = r0 + wv * 16 + kgrp * 4 + r;
      if (row < nrows) C[(size_t)row * FD + col] = acc2[t][r] + bl;
    }
  }
}

extern "C" void kernel_launch(void* const* d_in, const int* in_sizes, int n_in,
                              void* d_out, int out_size, void* d_ws, size_t ws_size,
                              hipStream_t stream)
{
  const float* x     = (const float*)d_in[0];
  const float* ew    = (const float*)d_in[1];
  const float* pvec  = (const float*)d_in[2];
  const float* w_ih  = (const float*)d_in[3];
  const float* w_hh  = (const float*)d_in[4];
  const float* b_ih  = (const float*)d_in[5];
  const float* b_hh  = (const float*)d_in[6];
  const float* w0    = (const float*)d_in[7];
  const float* w_lin = (const float*)d_in[8];
  const float* b_lin = (const float*)d_in[9];
  const int*   eidx  = (const int*)d_in[10];

  int N = in_sizes[0] / FD;
  int E = in_sizes[1];
  int NPART = (N + 255) >> PSH;
  const int* srcA = eidx;
  const int* dstA = eidx + E;

  char* base = (char*)d_ws;
  size_t off_ws = 0;
  auto take = [&](size_t bytes) -> void* {
    void* ptr = base + off_ws;
    off_ws = alignup256(off_ws + bytes);
    return ptr;
  };
  double* dvals = (double*)take((size_t)N * 8);
  unsigned* hist = (unsigned*)take(65536u * 4);
  unsigned* cnt = (unsigned*)take(4);
  unsigned* Bthr = (unsigned*)take(4);
  unsigned long long* ckey = (unsigned long long*)take((size_t)CAP * 8);
  unsigned* cidx = (unsigned*)take((size_t)CAP * 4);
  unsigned* sel_idx = (unsigned*)take(128 * 4);
  float* sel_ts = (float*)take(128 * 4);
  unsigned short* WbT = (unsigned short*)take(FD * FD * 2);
  unsigned short* wlb = (unsigned short*)take(FD * FD * 2);
  float* w_ihT = (float*)take(3 * FD * FD * 4);
  float* w_hhT = (float*)take(3 * FD * FD * 4);
  float* dinv = (float*)take((size_t)N * 4);
  unsigned* pcnt = (unsigned*)take((size_t)NPART_MAX * NBLK1 * 4);
  unsigned* basel = (unsigned*)take((size_t)NPART_MAX * NBLK1 * 4);
  unsigned* ptot = (unsigned*)take((size_t)NPART_MAX * 4);
  int* off = (int*)take(((size_t)N + 1) * 4);
  unsigned long long* epk2 = (unsigned long long*)take((size_t)E * 8);
  EdgeP* epk_b = (EdgeP*)take((size_t)E * 8);
  unsigned short* xb = (unsigned short*)take((size_t)N * FD * 2);
  unsigned short* aggb = (unsigned short*)take((size_t)N * FD * 2);
  float* out1 = (float*)d_out;

  hipMemsetAsync(hist, 0, 65536u * 4, stream);

  // L1: score_pack || part_count || transpose3 (interleaved branches)
  k_front<<<SCORE_BLKS + NBLK1 + TRANS_BLKS, 256, 0, stream>>>(
      x, pvec, dvals, hist, xb, cnt, N, dstA, pcnt, E, NPART,
      w_ih, w_hh, w_lin, w_ihT, w_hhT, wlb);
  // L2: find_thresh || scan_blocks
  k_mid1<<<1 + NPART, 1024, 0, stream>>>(hist, Bthr, pcnt, basel, ptot);
  // L3: part_place || compact
  k_mid2<<<NBLK1 + (N + 511) / 512, 512, 0, stream>>>(
      srcA, dstA, ew, ptot, basel, epk2, E, NPART,
      dvals, Bthr, ckey, cidx, cnt, N);
  // L4: topk_sort || part_csr
  k_mid3<<<1 + NPART, 512, 0, stream>>>(
      dvals, pvec, cnt, ckey, cidx, sel_idx, sel_ts,
      ptot, epk2, epk_b, off, dinv, N, NPART);
  // L5: gru_evolve || csr_gather4 (unified)
  k_gg<<<128 + (N * 64 + 255) / 256, 256, 0, stream>>>(
      x, sel_idx, sel_ts, w_ihT, w_hhT, b_ih, b_hh, w0, WbT,
      off, epk_b, dinv, xb, aggb, N);
  // L6: MFMA epilogue
  gemm_mfma<<<(N + 63) / 64, 256, 0, stream>>>(aggb, WbT, wlb, b_lin, out1, N);
}